// Round 3
// baseline (429.390 us; speedup 1.0000x reference)
//
#include <hip/hip_runtime.h>

#define HH 320
#define WW 320
#define BB 8
static constexpr float EPS = 1e-5f;

typedef __attribute__((ext_vector_type(8))) short bf16x8;
typedef __attribute__((ext_vector_type(4))) float f32x4;

__device__ inline float bf2f(unsigned short u) {
    union { unsigned int i; float f; } v; v.i = ((unsigned int)u) << 16; return v.f;
}
__device__ inline unsigned short f2bf(float f) {
    union { float f; unsigned int i; } v; v.f = f;
    unsigned int r = v.i + 0x7fffu + ((v.i >> 16) & 1u);
    return (unsigned short)(r >> 16);
}

// ---------------- NCHW fp32 -> NHWC bf16 (CIN=32) ----------------
__global__ __launch_bounds__(256) void prep_hwc(const float* __restrict__ in,
                                                unsigned short* __restrict__ out)
{
    __shared__ float sT[32][65];
    const int tid = threadIdx.x;
    const int x0  = blockIdx.x * 64;
    const int y   = blockIdx.y;
    const int b   = blockIdx.z;
    for (int e = tid; e < 32 * 64; e += 256) {
        int c = e >> 6, x = e & 63;
        sT[c][x] = in[(((size_t)(b * 32 + c) * HH) + y) * WW + x0 + x];
    }
    __syncthreads();
    for (int e = tid; e < 64 * 32; e += 256) {
        int x = e >> 5, c = e & 31;
        out[((((size_t)b * HH + y) * WW) + x0 + x) * 32 + c] = f2bf(sT[c][x]);
    }
}

// ---------------- weights OIHW fp32 -> [kk][oc][ic] bf16 ----------------
__global__ void wprep_kernel(const float* __restrict__ w1, const float* __restrict__ w2,
                             unsigned short* __restrict__ wt1, unsigned short* __restrict__ wt2)
{
    int i = blockIdx.x * 256 + threadIdx.x;
    if (i < 9 * 64 * 32) {
        int ic = i & 31, oc = (i >> 5) & 63, kk = i >> 11;
        wt1[i] = f2bf(w1[(oc * 32 + ic) * 9 + kk]);
    }
    if (i < 9 * 64 * 64) {
        int ic = i & 63, oc = (i >> 6) & 63, kk = i >> 12;
        wt2[i] = f2bf(w2[(oc * 64 + ic) * 9 + kk]);
    }
}

// ---------------- implicit-GEMM conv 3x3 via MFMA ----------------
// Block: 256 thr = 4 waves. Tile: 8 rows x 64 px x 64 oc. Wave w owns rows 2w,2w+1.
// Register tile per wave: af[8] x bfr[4] -> 32 MFMAs per 12 LDS reads.
// NORM_IN: relu((v-mean)*rstd) per channel while staging A.
// OUT_MODE 0: raw conv -> NHWC bf16 + partials.  OUT_MODE 3: raw conv -> NCHW fp32 + partials.
template<int CIN, int NORM_IN, int OUT_MODE>
__global__ __launch_bounds__(256, 2) void conv_mfma(
    const unsigned short* __restrict__ in_hwc,   // [B][H][W][CIN] bf16
    const float2* __restrict__ stats_in,         // [B*CIN] (NORM_IN)
    const unsigned short* __restrict__ wt,       // [9][64][CIN] bf16
    const float* __restrict__ bias,              // [64]
    unsigned short* __restrict__ out_hwc,        // MODE 0
    float* __restrict__ out_nchw,                // MODE 3
    float2* __restrict__ partials)               // [B*200][64]
{
    __shared__ __align__(16) char smem[81664];
    unsigned short* sA = (unsigned short*)smem;                 // [10][66][32] = 42240 B
    unsigned short* sW = (unsigned short*)(smem + 42240);       // [9][64][32]  = 36864 B
    float2* sRed   = (float2*)(smem + 79104);                   // [4][64] = 2048 B
    float2* sStats = (float2*)(smem + 81152);                   // [64]    = 512 B
    unsigned short* sOutb = (unsigned short*)smem;              // epilogue [4][64][80] = 40960 B
    float* sOutf = (float*)smem;                                // epilogue [4][64][69] = 70656 B

    const int tid = threadIdx.x;
    const int x0 = blockIdx.x * 64;
    const int y0 = blockIdx.y * 8;
    const int b  = blockIdx.z;
    const int w  = tid >> 6;
    const int l  = tid & 63;
    const int lm = l & 15;
    const int g  = l >> 4;

    if (NORM_IN) {
        if (tid < 64) sStats[tid] = stats_in[b * 64 + tid];
    }

    f32x4 acc[8][4];
#pragma unroll
    for (int fx = 0; fx < 8; ++fx)
#pragma unroll
        for (int fn = 0; fn < 4; ++fn)
            acc[fx][fn] = (f32x4){0.f, 0.f, 0.f, 0.f};

    for (int icc = 0; icc < CIN / 32; ++icc) {
        __syncthreads();
        // stage weights chunk: sW[kk][oc][32]
        for (int e = tid; e < 9 * 64 * 4; e += 256) {
            int icq = e & 3, oc = (e >> 2) & 63, kk = e >> 8;
            bf16x8 v = *(const bf16x8*)&wt[(size_t)(kk * 64 + oc) * CIN + icc * 32 + icq * 8];
            *(bf16x8*)&sW[(kk * 64 + oc) * 32 + icq * 8] = v;
        }
        // stage input tile + halo: sA[r 0..9][x 0..65][32]
        for (int e = tid; e < 10 * 66 * 4; e += 256) {
            int icq = e & 3, xr = e >> 2;
            int x = xr % 66, r = xr / 66;
            int gy = y0 + r - 1, gx = x0 + x - 1;
            unsigned short res[8];
            if ((unsigned)gy < HH && (unsigned)gx < WW) {
                bf16x8 v = *(const bf16x8*)&in_hwc[((((size_t)b * HH + gy) * WW) + gx) * CIN + icc * 32 + icq * 8];
                if (NORM_IN) {
#pragma unroll
                    for (int j = 0; j < 8; ++j) {
                        float2 ms = sStats[icc * 32 + icq * 8 + j];
                        float f = fmaxf((bf2f(((unsigned short*)&v)[j]) - ms.x) * ms.y, 0.f);
                        res[j] = f2bf(f);
                    }
                } else {
#pragma unroll
                    for (int j = 0; j < 8; ++j) res[j] = ((unsigned short*)&v)[j];
                }
            } else {
#pragma unroll
                for (int j = 0; j < 8; ++j) res[j] = 0;
            }
            *(bf16x8*)&sA[(r * 66 + x) * 32 + icq * 8] = *(bf16x8*)res;
        }
        __syncthreads();

#pragma unroll
        for (int kk = 0; kk < 9; ++kk) {
            const int ky = kk / 3, kx = kk % 3;
            bf16x8 af[8], bfr[4];
#pragma unroll
            for (int fx = 0; fx < 8; ++fx) {
                int rl = 2 * w + (fx >> 2) + ky;
                int xl = (fx & 3) * 16 + lm + kx;
                af[fx] = *(const bf16x8*)&sA[(rl * 66 + xl) * 32 + g * 8];
            }
#pragma unroll
            for (int fn = 0; fn < 4; ++fn)
                bfr[fn] = *(const bf16x8*)&sW[(kk * 64 + fn * 16 + lm) * 32 + g * 8];
#pragma unroll
            for (int fx = 0; fx < 8; ++fx)
#pragma unroll
                for (int fn = 0; fn < 4; ++fn)
                    acc[fx][fn] = __builtin_amdgcn_mfma_f32_16x16x32_bf16(
                        af[fx], bfr[fn], acc[fx][fn], 0, 0, 0);
        }
    }

    float bia[4];
#pragma unroll
    for (int fn = 0; fn < 4; ++fn) bia[fn] = bias[fn * 16 + lm];

    // ---- stats partials (per-block, per-oc) ----
#pragma unroll
    for (int fn = 0; fn < 4; ++fn) {
        float s = 0.f, ss = 0.f;
#pragma unroll
        for (int fx = 0; fx < 8; ++fx)
#pragma unroll
            for (int j = 0; j < 4; ++j) {
                float v = acc[fx][fn][j] + bia[fn];
                s += v; ss += v * v;
            }
        s  += __shfl_xor(s, 16);  s  += __shfl_xor(s, 32);
        ss += __shfl_xor(ss, 16); ss += __shfl_xor(ss, 32);
        if (l < 16) sRed[w * 64 + fn * 16 + l] = make_float2(s, ss);
    }
    __syncthreads();
    if (tid < 64) {
        float S = 0.f, SS = 0.f;
#pragma unroll
        for (int q = 0; q < 4; ++q) {
            float2 p = sRed[q * 64 + tid];
            S += p.x; SS += p.y;
        }
        partials[(((size_t)b * 40 + blockIdx.y) * 5 + blockIdx.x) * 64 + tid] = make_float2(S, SS);
    }

    // ---- coalesced store via LDS repack, two 4-row halves ----
    for (int half = 0; half < 2; ++half) {
        if ((w >> 1) == half) {
            int wh = w & 1;
#pragma unroll
            for (int fx = 0; fx < 8; ++fx) {
                int row_h = 2 * wh + (fx >> 2);
#pragma unroll
                for (int fn = 0; fn < 4; ++fn) {
                    int oc = fn * 16 + lm;
#pragma unroll
                    for (int j = 0; j < 4; ++j) {
                        float v = acc[fx][fn][j] + bia[fn];
                        int px = (fx & 3) * 16 + g * 4 + j;
                        if (OUT_MODE == 0)
                            sOutb[(row_h * 64 + px) * 80 + oc] = f2bf(v);
                        else
                            sOutf[(row_h * 64 + px) * 69 + oc] = v;
                    }
                }
            }
        }
        __syncthreads();
        if (OUT_MODE == 0) {
            for (int e = tid; e < 2048; e += 256) {
                int ocq = e & 7, px = (e >> 3) & 63, r = e >> 9;
                int row = y0 + half * 4 + r;
                *(bf16x8*)&out_hwc[(((size_t)b * HH + row) * WW + x0 + px) * 64 + ocq * 8] =
                    *(const bf16x8*)&sOutb[(r * 64 + px) * 80 + ocq * 8];
            }
        } else {
            for (int e = tid; e < 4096; e += 256) {
                int xq = e & 15, rc = e >> 4;
                int r = rc >> 6, c = rc & 63;
                int row = y0 + half * 4 + r;
                float4 v;
                v.x = sOutf[(r * 64 + xq * 4 + 0) * 69 + c];
                v.y = sOutf[(r * 64 + xq * 4 + 1) * 69 + c];
                v.z = sOutf[(r * 64 + xq * 4 + 2) * 69 + c];
                v.w = sOutf[(r * 64 + xq * 4 + 3) * 69 + c];
                *(float4*)&out_nchw[(((size_t)(b * 64 + c) * HH) + row) * WW + x0 + xq * 4] = v;
            }
        }
        __syncthreads();
    }
}

// ---------------- partials -> (mean, rstd) ----------------
__global__ __launch_bounds__(256) void reduce_stats(const float2* __restrict__ partials,
                                                    float2* __restrict__ stats)
{
    const int b  = blockIdx.x;
    const int oc = threadIdx.x & 63;
    const int q  = threadIdx.x >> 6;
    float s = 0.f, ss = 0.f;
    for (int i = q; i < 200; i += 4) {
        float2 p = partials[((size_t)b * 200 + i) * 64 + oc];
        s += p.x; ss += p.y;
    }
    __shared__ float2 red[4][64];
    red[q][oc] = make_float2(s, ss);
    __syncthreads();
    if (threadIdx.x < 64) {
        float S = 0.f, SS = 0.f;
#pragma unroll
        for (int k = 0; k < 4; ++k) { S += red[k][threadIdx.x].x; SS += red[k][threadIdx.x].y; }
        const float n = (float)(HH * WW);
        float mean = S / n;
        float var  = fmaxf(SS / n - mean * mean, 0.f);
        stats[b * 64 + threadIdx.x] = make_float2(mean, rsqrtf(var + EPS));
    }
}

// ---------------- in-place normalize + relu on NCHW fp32 ----------------
__global__ __launch_bounds__(256) void finalize_kernel(float* __restrict__ out,
                                                       const float2* __restrict__ stats)
{
    const int bc  = blockIdx.x >> 2;
    const int seg = blockIdx.x & 3;
    float2 ms = stats[bc];
    float4* p = (float4*)(out + (size_t)bc * (HH * WW));
    const int n4 = HH * WW / 4;                 // 25600
    for (int i = seg * (n4 / 4) + threadIdx.x; i < (seg + 1) * (n4 / 4); i += 256) {
        float4 v = p[i];
        v.x = fmaxf((v.x - ms.x) * ms.y, 0.f);
        v.y = fmaxf((v.y - ms.x) * ms.y, 0.f);
        v.z = fmaxf((v.z - ms.x) * ms.y, 0.f);
        v.w = fmaxf((v.w - ms.x) * ms.y, 0.f);
        p[i] = v;
    }
}

extern "C" void kernel_launch(void* const* d_in, const int* in_sizes, int n_in,
                              void* d_out, int out_size, void* d_ws, size_t ws_size,
                              hipStream_t stream)
{
    const float* x  = (const float*)d_in[0];
    const float* w1 = (const float*)d_in[1];
    const float* b1 = (const float*)d_in[2];
    const float* w2 = (const float*)d_in[3];
    const float* b2 = (const float*)d_in[4];
    float* out = (float*)d_out;

    char* ws = (char*)d_ws;
    size_t off = 0;
    unsigned short* h_hwc = (unsigned short*)(ws + off); off += (size_t)BB * HH * WW * 64 * 2;
    unsigned short* x_hwc = (unsigned short*)(ws + off); off += (size_t)BB * HH * WW * 32 * 2;
    unsigned short* wt1   = (unsigned short*)(ws + off); off += 9 * 64 * 32 * 2;
    unsigned short* wt2   = (unsigned short*)(ws + off); off += 9 * 64 * 64 * 2;
    float2* partials      = (float2*)(ws + off);         off += (size_t)BB * 200 * 64 * sizeof(float2);
    float2* stats1        = (float2*)(ws + off);         off += 512 * sizeof(float2);
    float2* stats2        = (float2*)(ws + off);         off += 512 * sizeof(float2);

    dim3 cgrid(5, 40, BB);

    prep_hwc<<<dim3(5, HH, BB), 256, 0, stream>>>(x, x_hwc);
    wprep_kernel<<<144, 256, 0, stream>>>(w1, w2, wt1, wt2);

    // conv1: raw bf16 NHWC + partials
    conv_mfma<32, 0, 0><<<cgrid, 256, 0, stream>>>(x_hwc, nullptr, wt1, b1,
                                                   h_hwc, nullptr, partials);
    reduce_stats<<<BB, 256, 0, stream>>>(partials, stats1);
    // conv2: normalized input, raw fp32 NCHW + partials (single pass)
    conv_mfma<64, 1, 3><<<cgrid, 256, 0, stream>>>(h_hwc, stats1, wt2, b2,
                                                   nullptr, out, partials);
    reduce_stats<<<BB, 256, 0, stream>>>(partials, stats2);
    // in-place normalize + relu on d_out
    finalize_kernel<<<BB * 64 * 4, 256, 0, stream>>>(out, stats2);
}